// Round 3
// baseline (238.354 us; speedup 1.0000x reference)
//
#include <hip/hip_runtime.h>
#include <stdint.h>

// GPUHausdorffLoss — R12: K1 stall surgery.
//  (a) threefry as 8 explicitly-interleaved chains (X0[8]/X1[8], static idx,
//      unrolled) + __launch_bounds__(256,3) so all states stay in VGPRs ->
//      dep-chain latency hidden by ILP, not just occupancy.
//  (b) halo cols via clamped scalar global loads issued with the row float4s
//      (removes ds_swizzle + lgkmcnt wait from promote's critical path).
//  (c) candidate staging: ONE atomicAdd(popc) per lane, then dependent-free
//      stores (was: one LDS-atomic round-trip per candidate).
//  K1 sobel_cand (2048 blk = 128 img-sides x 16 slices; wave w of 4 owns rows
//     [slice*32+8w, +8), lane owns 8 cols).
//  K2 resolve (128 blk, 1/img): LDS-staged candidates, coarse/fine radix
//     select + exact ties; exact slow-path rebuild (statistically never).
//  K3 haus (512 blk): per (img,dir,seg) partial max of min d^2 -> g_hpart.
//  K4 fin (1x64): reduce 8 partials/img, clip, mean -> out[0].

#define HH 512
#define WW 512
#define NPIX (HH * WW)
#define NSEL 1000
#define SLICE_CAP 320
#define CUTM (253u << 14)                     // m-threshold (top 3 of 256 bins)
#define BITCUT ((((253u << 15) - 1u)) << 9)   // bits >= BITCUT  <=>  m >= CUTM
#define ROWS_PER 32

#if __has_builtin(__builtin_amdgcn_alignbit)
__device__ __forceinline__ uint32_t rotl32(uint32_t x, int r) {
  return __builtin_amdgcn_alignbit(x, x, (32 - r) & 31);
}
#else
__device__ __forceinline__ uint32_t rotl32(uint32_t x, int r) {
  return (x << r) | (x >> (32 - r));
}
#endif

// JAX threefry2x32: 20 rounds, key schedule every 4.
__device__ __forceinline__ void tf2x32(uint32_t k0, uint32_t k1,
                                       uint32_t c0, uint32_t c1,
                                       uint32_t& o0, uint32_t& o1) {
  uint32_t ks2 = k0 ^ k1 ^ 0x1BD11BDAu;
  uint32_t x0 = c0 + k0, x1 = c1 + k1;
#define TF_R(r) { x0 += x1; x1 = rotl32(x1, (r)); x1 ^= x0; }
  TF_R(13) TF_R(15) TF_R(26) TF_R(6)
  x0 += k1;  x1 += ks2 + 1u;
  TF_R(17) TF_R(29) TF_R(16) TF_R(24)
  x0 += ks2; x1 += k0 + 2u;
  TF_R(13) TF_R(15) TF_R(26) TF_R(6)
  x0 += k0;  x1 += k1 + 3u;
  TF_R(17) TF_R(29) TF_R(16) TF_R(24)
  x0 += k1;  x1 += ks2 + 4u;
  TF_R(13) TF_R(15) TF_R(26) TF_R(6)
  x0 += ks2; x1 += k0 + 5u;
#undef TF_R
  o0 = x0; o1 = x1;
}

// Exact rank value of score = 2.0f + uniform(bits): bits(score) - bits(2.0f).
__device__ __forceinline__ uint32_t m_from_bits(uint32_t bits) {
  float noise = __uint_as_float((bits >> 9) | 0x3F800000u) - 1.0f;
  float score = 2.0f + noise;
  return __float_as_uint(score) - 0x40000000u;  // 0 .. 0x400000 inclusive
}

__device__ __forceinline__ uint32_t pixel_m(uint32_t k0, uint32_t k1, int p) {
  uint32_t b1, b2;
  tf2x32(k0, k1, 0u, (uint32_t)p, b1, b2);
  return m_from_bits(b1 ^ b2);
}

__device__ __forceinline__ float sigf(float x) { return 1.0f / (1.0f + __expf(-x)); }

__device__ __forceinline__ float ldval(const float* __restrict__ img, int r, int c, bool isPred) {
  if (r < 0 || r > HH - 1 || c < 0 || c > WW - 1) return 0.0f;  // conv zero-pad (post-sigmoid)
  float v = img[(size_t)r * WW + c];
  return isPred ? sigf(v) : v;
}

__device__ __forceinline__ uint32_t pack_pt(uint32_t p) {
  return ((p >> 9) << 16) | (p & 511u);
}

// ---------------- K1 ----------------
// Wave spans a full 512-col row: lane owns cols [8*lane, 8*lane+8).
// Rolled row loop; named P/Q/R ring (static indices). One raw row in flight:
// float4 x2 + 2 clamped halo scalars, issued at iter r, promoted at iter r+1
// (hash block covers the latency). sched_barrier(0) pins load issue.
template <bool PRED>
__device__ __forceinline__ void sobel_body(const float* __restrict__ img, int b,
                                           int slice, int t,
                                           unsigned long long* stage, int* s_cn,
                                           int* s_cv) {
  const int lane = t & 63, w = t >> 6;
  const int rbase = slice * ROWS_PER + 8 * w;  // this wave's first compute row
  uint32_t k0, k1;
  tf2x32(0u, 1u, 0u, (uint32_t)b, k0, k1);
  k0 = __builtin_amdgcn_readfirstlane(k0);  // wave-uniform -> pin to SGPR
  k1 = __builtin_amdgcn_readfirstlane(k1);
  const uint32_t ks2 = k0 ^ k1 ^ 0x1BD11BDAu;

  float P[10], Q[10], R[10];  // processed 3-row window (static indices only)
  float4 na, nb;              // raw row in flight (pre-sigmoid)
  float hl, hr;               // raw halo scalars in flight
  int cnt = 0;
  const uint32_t pbase = (uint32_t)((rbase << 9) + (lane << 3));
  const int offL = (lane == 0) ? 0 : -1;   // clamped halo offsets (in-bounds)
  const int offR = (lane == 63) ? 7 : 8;

  auto issue = [&](int rn) {  // issue-only raw loads; no dependent ops
    if ((unsigned)rn < (unsigned)HH) {  // wave-uniform branch
      const float* rp = img + ((size_t)rn << 9) + (lane << 3);
      na = *(const float4*)rp;
      nb = *(const float4*)(rp + 4);
      hl = rp[offL];
      hr = rp[offR];
    }
  };
  auto promote = [&](float (&vv)[10], int rn) {  // raw -> processed
    if ((unsigned)rn < (unsigned)HH) {  // wave-uniform branch
      float4 x = na, y = nb;
      float l = hl, r = hr;
      if (PRED) {
        x.x = sigf(x.x); x.y = sigf(x.y); x.z = sigf(x.z); x.w = sigf(x.w);
        y.x = sigf(y.x); y.y = sigf(y.y); y.z = sigf(y.z); y.w = sigf(y.w);
        l = sigf(l); r = sigf(r);
      }
      vv[1] = x.x; vv[2] = x.y; vv[3] = x.z; vv[4] = x.w;
      vv[5] = y.x; vv[6] = y.y; vv[7] = y.z; vv[8] = y.w;
      vv[0] = (lane == 0) ? 0.0f : l;   // conv zero-pad at col -1
      vv[9] = (lane == 63) ? 0.0f : r;  // conv zero-pad at col 512
    } else {
#pragma unroll
      for (int i = 0; i < 10; ++i) vv[i] = 0.0f;
    }
  };

  // prologue: P = row rbase-1, Q = row rbase; row rbase+1 left in flight
  issue(rbase - 1); promote(P, rbase - 1);
  issue(rbase);     promote(Q, rbase);
  issue(rbase + 1);

#pragma unroll 1
  for (int r = 0; r < 8; ++r) {  // compute row rbase+r — ROLLED
    promote(R, rbase + r + 1);       // consume in-flight raw (loaded 1 body ago)
    if (r < 7) issue(rbase + r + 2); // next raw; reads of na/nb already done
    __builtin_amdgcn_sched_barrier(0);  // pin load issue above the hash block

    const uint32_t prow = pbase + ((uint32_t)r << 9);
    // ---- threefry: 8 explicitly-interleaved chains (ILP by construction) ----
    uint32_t X0[8], X1[8];
    const uint32_t pk = prow + k1;
#pragma unroll
    for (int j = 0; j < 8; ++j) { X0[j] = k0; X1[j] = pk + (uint32_t)j; }
#define RND(rr)                                                         \
  _Pragma("unroll") for (int j = 0; j < 8; ++j) {                       \
    X0[j] += X1[j];                                                     \
    X1[j] = rotl32(X1[j], (rr)) ^ X0[j];                                \
  }
#define INJ(ka, kb, i)                                                  \
  _Pragma("unroll") for (int j = 0; j < 8; ++j) {                       \
    X0[j] += (ka);                                                      \
    X1[j] += (kb) + (uint32_t)(i);                                      \
  }
    RND(13) RND(15) RND(26) RND(6)  INJ(k1, ks2, 1)
    RND(17) RND(29) RND(16) RND(24) INJ(ks2, k0, 2)
    RND(13) RND(15) RND(26) RND(6)  INJ(k0, k1, 3)
    RND(17) RND(29) RND(16) RND(24) INJ(k1, ks2, 4)
    RND(13) RND(15) RND(26) RND(6)  INJ(ks2, k0, 5)
#undef RND
#undef INJ
    uint32_t bits[8];
#pragma unroll
    for (int j = 0; j < 8; ++j) bits[j] = X0[j] ^ X1[j];

    // ---- sobel + masks ----
    float da[10], e[10];
#pragma unroll
    for (int k = 0; k < 10; ++k) {
      da[k] = R[k] - P[k];
      e[k] = P[k] + 2.0f * Q[k] + R[k];
    }
    uint32_t candmask = 0;
#pragma unroll
    for (int j = 0; j < 8; ++j) {
      float gx = e[j + 2] - e[j];
      float gy = da[j] + 2.0f * da[j + 1] + da[j + 2];
      bool vld = (gx * gx + gy * gy + 1e-8f) > 0.01f;  // sqrt(x)>0.1 <=> x>0.01
      cnt += vld ? 1 : 0;
      candmask |= ((vld && bits[j] >= BITCUT) ? 1u : 0u) << j;
    }
    if (candmask) {  // rare: ~1.2% of pixels -> ONE atomic, then free stores
      int base = atomicAdd(s_cn, __popc(candmask));
      do {
        int j = __ffs(candmask) - 1;
        candmask &= candmask - 1;
        if (base < SLICE_CAP) {
          uint32_t m = m_from_bits(bits[j]);
          stage[base] = ((unsigned long long)m << 32) | (prow + (uint32_t)j);
        }
        ++base;
      } while (candmask);
    }
#pragma unroll
    for (int k = 0; k < 10; ++k) { P[k] = Q[k]; Q[k] = R[k]; }  // rotate ring
  }
#pragma unroll
  for (int o = 32; o > 0; o >>= 1) cnt += __shfl_down(cnt, o);
  if (lane == 0) atomicAdd(s_cv, cnt);
}

__global__ __launch_bounds__(256, 3) void sobel_cand(
    const float* __restrict__ pred, const float* __restrict__ tgt,
    int2* __restrict__ g_scnt, unsigned long long* __restrict__ g_cand) {
  const int bid = blockIdx.x;
  const int b = bid >> 4, s = bid & 15;
  const int t = threadIdx.x;
  __shared__ unsigned long long stage[SLICE_CAP];
  __shared__ int s_cn, s_cv;
  if (t == 0) { s_cn = 0; s_cv = 0; }
  __syncthreads();
  if (b < 64) sobel_body<true>(pred + (size_t)b * NPIX, b, s, t, stage, &s_cn, &s_cv);
  else        sobel_body<false>(tgt + (size_t)(b - 64) * NPIX, b, s, t, stage, &s_cn, &s_cv);
  __syncthreads();
  const int raw = s_cn;
  const int n = raw < SLICE_CAP ? raw : SLICE_CAP;
  for (int i = t; i < n; i += 256) g_cand[(size_t)bid * SLICE_CAP + i] = stage[i];
  if (t == 0) g_scnt[bid] = make_int2(s_cv, raw);
}

// ---------------- K2 resolve (1 block per image-side) ----------------
// Candidates staged ONCE into LDS (compacted, order-free — all selection
// passes are order-insensitive), then 3 passes run out of LDS.
__global__ __launch_bounds__(256) void resolve_kernel(
    const float* __restrict__ pred, const float* __restrict__ tgt,
    const int2* __restrict__ g_scnt, unsigned long long* __restrict__ g_cand,
    uint32_t* __restrict__ g_pts, int* __restrict__ g_counts) {
  const int img = blockIdx.x;
  const int t = threadIdx.x;

  __shared__ unsigned long long cand_s[16 * SLICE_CAP];  // 40 KB
  __shared__ int segc[16];
  __shared__ int s_scx[16], s_scy[16];
  __shared__ int s_info[4];  // cv, cnt_hi_sum, ovf, ncand_rebuilt
  __shared__ int ch[256];
  __shared__ int fh[1024];
  __shared__ int aux[256];
  __shared__ unsigned long long ties[256];
  __shared__ int s_pos, s_nt, s_T1, s_r1, s_T2, s_r2, s_n;

  if (t < 16) {
    int2 v = g_scnt[img * 16 + t];
    s_scx[t] = v.x; s_scy[t] = v.y;
    segc[t] = v.y < SLICE_CAP ? v.y : SLICE_CAP;
  }
  if (t == 0) { s_pos = 0; s_nt = 0; s_n = 0; }
  __syncthreads();
  if (t == 0) {
    int cv = 0, hi = 0, ovf = 0;
    for (int s = 0; s < 16; ++s) {
      cv += s_scx[s]; hi += s_scy[s];
      if (s_scy[s] > SLICE_CAP) ovf = 1;
    }
    s_info[0] = cv; s_info[1] = hi; s_info[2] = ovf;
  }
  __syncthreads();
  const int cv = s_info[0];
  if (cv == 0) {  // center fallback
    if (t == 0) { g_pts[img * NSEL] = (256u << 16) | 256u; g_counts[img] = 1; }
    return;
  }
  const int need = cv < NSEL ? cv : NSEL;
  bool slow = (s_info[2] != 0) || (s_info[1] < need);

  unsigned long long* C = g_cand + (size_t)img * 16 * SLICE_CAP;
  int ncand = 0;

  if (slow) {
    // ---- exact rebuild (statistically never taken): rescan whole image ----
    const bool isPred = img < 64;
    const float* im = isPred ? pred + (size_t)img * NPIX : tgt + (size_t)(img - 64) * NPIX;
    uint32_t k0, k1;
    tf2x32(0u, 1u, 0u, (uint32_t)img, k0, k1);
    ch[t] = 0;
    __syncthreads();
    for (int p = t; p < NPIX; p += 256) {
      int r = p >> 9, c = p & 511;
      float gx = (ldval(im, r - 1, c + 1, isPred) - ldval(im, r - 1, c - 1, isPred)) +
                 2.0f * (ldval(im, r, c + 1, isPred) - ldval(im, r, c - 1, isPred)) +
                 (ldval(im, r + 1, c + 1, isPred) - ldval(im, r + 1, c - 1, isPred));
      float gy = (ldval(im, r + 1, c - 1, isPred) - ldval(im, r - 1, c - 1, isPred)) +
                 2.0f * (ldval(im, r + 1, c, isPred) - ldval(im, r - 1, c, isPred)) +
                 (ldval(im, r + 1, c + 1, isPred) - ldval(im, r - 1, c + 1, isPred));
      if ((gx * gx + gy * gy + 1e-8f) > 0.01f) {
        uint32_t m = pixel_m(k0, k1, p);
        uint32_t cb = m >> 14; if (cb > 255u) cb = 255u;
        atomicAdd(&ch[cb], 1);
      }
    }
    __syncthreads();
    {
      aux[t] = ch[t];
      __syncthreads();
      for (int o = 1; o < 256; o <<= 1) {
        int v = (t + o < 256) ? aux[t + o] : 0;
        __syncthreads();
        aux[t] += v;
        __syncthreads();
      }
      int nx = (t + 1 < 256) ? aux[t + 1] : 0;
      if (aux[t] >= need && nx < need) s_T1 = t;
      __syncthreads();
    }
    const uint32_t Tc = (uint32_t)s_T1;
    if (t == 0) s_info[3] = 0;
    __syncthreads();
    for (int p = t; p < NPIX; p += 256) {
      int r = p >> 9, c = p & 511;
      float gx = (ldval(im, r - 1, c + 1, isPred) - ldval(im, r - 1, c - 1, isPred)) +
                 2.0f * (ldval(im, r, c + 1, isPred) - ldval(im, r, c - 1, isPred)) +
                 (ldval(im, r + 1, c + 1, isPred) - ldval(im, r + 1, c - 1, isPred));
      float gy = (ldval(im, r + 1, c - 1, isPred) - ldval(im, r - 1, c - 1, isPred)) +
                 2.0f * (ldval(im, r + 1, c, isPred) - ldval(im, r - 1, c, isPred)) +
                 (ldval(im, r + 1, c + 1, isPred) - ldval(im, r - 1, c + 1, isPred));
      if ((gx * gx + gy * gy + 1e-8f) > 0.01f) {
        uint32_t m = pixel_m(k0, k1, p);
        uint32_t cb = m >> 14; if (cb > 255u) cb = 255u;
        if (cb >= Tc) {
          int i = atomicAdd(&s_info[3], 1);
          if (i < 16 * SLICE_CAP) C[i] = ((unsigned long long)m << 32) | (uint32_t)p;
        }
      }
    }
    __syncthreads();
    ncand = s_info[3] < 16 * SLICE_CAP ? s_info[3] : 16 * SLICE_CAP;
  }

  // ---- stage candidates into LDS (order-free compaction) ----
  if (slow) {
    for (int i = t; i < ncand; i += 256) cand_s[i] = C[i];
    if (t == 0) s_n = ncand;
  } else {
    for (int i = t; i < 16 * SLICE_CAP; i += 256) {
      int s = i / SLICE_CAP;
      int o = i - s * SLICE_CAP;
      if (o < segc[s]) {
        unsigned long long e = C[i];
        cand_s[atomicAdd(&s_n, 1)] = e;
      }
    }
  }
  // zero histograms while staging is in flight
  ch[t] = 0;
  for (int i = t; i < 1024; i += 256) fh[i] = 0;
  __syncthreads();
  const int n = s_n;

  // ---- selection over LDS candidates ----
  for (int i = t; i < n; i += 256) {
    uint32_t m = (uint32_t)(cand_s[i] >> 32);
    uint32_t cb = m >> 14; if (cb > 255u) cb = 255u;
    atomicAdd(&ch[cb], 1);
  }
  __syncthreads();
  {
    aux[t] = ch[t];
    __syncthreads();
    for (int o = 1; o < 256; o <<= 1) {
      int v = (t + o < 256) ? aux[t + o] : 0;
      __syncthreads();
      aux[t] += v;
      __syncthreads();
    }
    int nx = (t + 1 < 256) ? aux[t + 1] : 0;
    if (aux[t] >= need && nx < need) { s_T1 = t; s_r1 = need - nx; }
    __syncthreads();
  }
  const uint32_t T1 = (uint32_t)s_T1;
  const int r1 = s_r1;
  const uint32_t baseM = T1 << 14;

  for (int i = t; i < n; i += 256) {
    unsigned long long e = cand_s[i];
    uint32_t m = (uint32_t)(e >> 32), p = (uint32_t)e;
    uint32_t cb = m >> 14; if (cb > 255u) cb = 255u;
    if (cb > T1) {
      int pos = atomicAdd(&s_pos, 1);
      g_pts[img * NSEL + pos] = pack_pt(p);
    } else if (cb == T1) {
      uint32_t f = (m - baseM) >> 4; if (f > 1023u) f = 1023u;
      atomicAdd(&fh[f], 1);
    }
  }
  __syncthreads();
  {
    int base = 4 * t, sv = 0;
    for (int j = 3; j >= 0; --j) { sv += fh[base + j]; fh[base + j] = sv; }
    aux[t] = sv;
    __syncthreads();
    for (int o = 1; o < 256; o <<= 1) {
      int v = (t + o < 256) ? aux[t + o] : 0;
      __syncthreads();
      aux[t] += v;
      __syncthreads();
    }
    int add = (t < 255) ? aux[t + 1] : 0;
    for (int j = 0; j < 4; ++j) fh[base + j] += add;
    __syncthreads();
    for (int j = 0; j < 4; ++j) {
      int idx = base + j;
      int sfx = fh[idx];
      int nx = (idx < 1023) ? fh[idx + 1] : 0;
      if (sfx >= r1 && nx < r1) { s_T2 = idx; s_r2 = r1 - nx; }
    }
    __syncthreads();
  }
  const int T2 = s_T2, r2 = s_r2;
  for (int i = t; i < n; i += 256) {
    unsigned long long e = cand_s[i];
    uint32_t m = (uint32_t)(e >> 32), p = (uint32_t)e;
    uint32_t cb = m >> 14; if (cb > 255u) cb = 255u;
    if (cb == T1) {
      uint32_t f = (m - baseM) >> 4; if (f > 1023u) f = 1023u;
      if ((int)f > T2) {
        int pos = atomicAdd(&s_pos, 1);
        g_pts[img * NSEL + pos] = pack_pt(p);
      } else if ((int)f == T2) {
        int j = atomicAdd(&s_nt, 1);
        if (j < 256) ties[j] = e;
      }
    }
  }
  __syncthreads();
  int nt = s_nt < 256 ? s_nt : 256;
  for (int i = t; i < nt; i += 256) {
    unsigned long long e = ties[i];
    uint32_t mi = (uint32_t)(e >> 32), pi = (uint32_t)e;
    int rank = 0;
    for (int j = 0; j < nt; ++j) {
      unsigned long long e2 = ties[j];
      uint32_t mj = (uint32_t)(e2 >> 32), pj = (uint32_t)e2;
      rank += (mj > mi) || (mj == mi && pj < pi);
    }
    if (rank < r2) {
      int pos = atomicAdd(&s_pos, 1);
      g_pts[img * NSEL + pos] = pack_pt(pi);
    }
  }
  __syncthreads();
  if (t == 0) g_counts[img] = s_pos;  // == need
}

// ---------------- K3 ----------------
__global__ __launch_bounds__(256) void haus_kernel(
    const uint32_t* __restrict__ g_pts, const int* __restrict__ g_counts,
    float* __restrict__ g_hpart) {
  const int bid = blockIdx.x;
  const int img = bid >> 3;
  const int dir = (bid >> 2) & 1;
  const int seg = bid & 3;
  const int t = threadIdx.x;
  const int iOwn = dir ? 64 + img : img;
  const int iOth = dir ? img : 64 + img;
  const int nOwn = g_counts[iOwn];
  const int nOth = g_counts[iOth];
  __shared__ float2 o[NSEL];
  __shared__ float red[256];
  for (int i = t; i < nOth; i += 256) {
    uint32_t v = g_pts[iOth * NSEL + i];
    o[i] = make_float2((float)(v >> 16), (float)(v & 0xFFFFu));
  }
  __syncthreads();
  float best = 0.0f;
  const int lo = seg * 250;
  const int hi = min(nOwn, lo + 250);
  for (int i = lo + t; i < hi; i += 256) {
    uint32_t v = g_pts[iOwn * NSEL + i];
    float pr = (float)(v >> 16), pc = (float)(v & 0xFFFFu);
    // 4 independent accumulators: break the serial fmin dependency chain
    float mn0 = 3.4e38f, mn1 = 3.4e38f, mn2 = 3.4e38f, mn3 = 3.4e38f;
    int j = 0;
    for (; j + 3 < nOth; j += 4) {
      float dr0 = pr - o[j].x,     dc0 = pc - o[j].y;
      float dr1 = pr - o[j + 1].x, dc1 = pc - o[j + 1].y;
      float dr2 = pr - o[j + 2].x, dc2 = pc - o[j + 2].y;
      float dr3 = pr - o[j + 3].x, dc3 = pc - o[j + 3].y;
      mn0 = fminf(mn0, dr0 * dr0 + dc0 * dc0);
      mn1 = fminf(mn1, dr1 * dr1 + dc1 * dc1);
      mn2 = fminf(mn2, dr2 * dr2 + dc2 * dc2);
      mn3 = fminf(mn3, dr3 * dr3 + dc3 * dc3);
    }
    for (; j < nOth; ++j) {
      float dr = pr - o[j].x, dc = pc - o[j].y;
      mn0 = fminf(mn0, dr * dr + dc * dc);
    }
    float mn = fminf(fminf(mn0, mn1), fminf(mn2, mn3));
    best = fmaxf(best, mn);
  }
  red[t] = best;
  __syncthreads();
  for (int st = 128; st > 0; st >>= 1) {
    if (t < st) red[t] = fmaxf(red[t], red[t + st]);
    __syncthreads();
  }
  if (t == 0) g_hpart[bid] = red[0];
}

// ---------------- K4 ----------------
__global__ __launch_bounds__(64) void fin_kernel(const float* __restrict__ g_hpart,
                                                 float* __restrict__ out) {
  const int t = threadIdx.x;  // one thread per image
  float mx = 0.0f;
  for (int j = 0; j < 8; ++j) mx = fmaxf(mx, g_hpart[t * 8 + j]);
  float diag = sqrtf((float)(HH * HH + WW * WW));
  float hd = sqrtf(fmaxf(mx, 0.0f)) / diag;
  hd = fminf(fmaxf(hd, 0.0f), 0.1f);
  float s = hd;
  for (int o = 32; o > 0; o >>= 1) s += __shfl_down(s, o);
  if (t == 0) out[0] = s * 0.015625f;
}

// ---------------- workspace layout (bytes) — nothing pre-zeroed ----------
#define WS_SCNT   0u                          // 2048*8 = 16384
#define WS_COUNTS 16384u                      // 512
#define WS_HPART  (WS_COUNTS + 512u)          // 2048
#define WS_PTS    (WS_HPART + 2048u)          // 512000
#define WS_CAND   (WS_PTS + 512000u)          // 2048*320*8 = 5242880  (~5.5 MB total)

extern "C" void kernel_launch(void* const* d_in, const int* in_sizes, int n_in,
                              void* d_out, int out_size, void* d_ws, size_t ws_size,
                              hipStream_t stream) {
  const float* pred = (const float*)d_in[0];
  const float* tgt = (const float*)d_in[1];
  float* out = (float*)d_out;
  char* ws = (char*)d_ws;
  int2* g_scnt = (int2*)(ws + WS_SCNT);
  int* g_counts = (int*)(ws + WS_COUNTS);
  float* g_hpart = (float*)(ws + WS_HPART);
  uint32_t* g_pts = (uint32_t*)(ws + WS_PTS);
  unsigned long long* g_cand = (unsigned long long*)(ws + WS_CAND);

  sobel_cand<<<2048, 256, 0, stream>>>(pred, tgt, g_scnt, g_cand);
  resolve_kernel<<<128, 256, 0, stream>>>(pred, tgt, g_scnt, g_cand, g_pts, g_counts);
  haus_kernel<<<512, 256, 0, stream>>>(g_pts, g_counts, g_hpart);
  fin_kernel<<<1, 64, 0, stream>>>(g_hpart, out);
}

// Round 4
// 233.289 us; speedup vs baseline: 1.0217x; 1.0217x over previous
//
#include <hip/hip_runtime.h>
#include <stdint.h>

// GPUHausdorffLoss — R13: K1 = R11 memory structure (float4 loads + shuffle
// halo — best measured) + R12 interleaved 8-chain hash + batched atomic, and
// the decisive change: rotates forced to single v_alignbit_b32 via inline asm
// (recent LLVM removed __builtin_amdgcn_alignbit; the (x<<r)|(x>>(32-r))
// fallback may lower to 3 insts — 20 rotates/px would inflate the hash ~55%,
// matching the measured 92us busy vs ~50us static-count floor).
//  K1 sobel_cand (2048 blk = 128 img-sides x 16 slices; wave w of 4 owns rows
//     [slice*32+8w, +8), lane owns 8 cols).
//  K2 resolve (128 blk, 1/img): LDS-staged candidates, coarse/fine radix
//     select + exact ties; exact slow-path rebuild (statistically never).
//  K3 haus (512 blk): per (img,dir,seg) partial max of min d^2 -> g_hpart.
//  K4 fin (1x64): reduce 8 partials/img, clip, mean -> out[0].

#define HH 512
#define WW 512
#define NPIX (HH * WW)
#define NSEL 1000
#define SLICE_CAP 320
#define CUTM (253u << 14)                     // m-threshold (top 3 of 256 bins)
#define BITCUT ((((253u << 15) - 1u)) << 9)   // bits >= BITCUT  <=>  m >= CUTM
#define ROWS_PER 32

#if __has_builtin(__builtin_amdgcn_alignbit)
__device__ __forceinline__ uint32_t rotl32(uint32_t x, int r) {
  return __builtin_amdgcn_alignbit(x, x, (32 - r) & 31);
}
#else
__device__ __forceinline__ uint32_t rotl32(uint32_t x, int r) {
  return (x << r) | (x >> (32 - r));
}
#endif

// Guaranteed single-instruction rotate: v_alignbit_b32 d, x, x, (32-R).
// VOP3; shift amounts {19,17,6,26,15,3,16,8} are all valid inline constants.
template <int R>
__device__ __forceinline__ uint32_t rotlT(uint32_t x) {
  uint32_t d;
  asm("v_alignbit_b32 %0, %1, %1, %2" : "=v"(d) : "v"(x), "n"(32 - R));
  return d;
}

// JAX threefry2x32: 20 rounds, key schedule every 4.
__device__ __forceinline__ void tf2x32(uint32_t k0, uint32_t k1,
                                       uint32_t c0, uint32_t c1,
                                       uint32_t& o0, uint32_t& o1) {
  uint32_t ks2 = k0 ^ k1 ^ 0x1BD11BDAu;
  uint32_t x0 = c0 + k0, x1 = c1 + k1;
#define TF_R(r) { x0 += x1; x1 = rotl32(x1, (r)); x1 ^= x0; }
  TF_R(13) TF_R(15) TF_R(26) TF_R(6)
  x0 += k1;  x1 += ks2 + 1u;
  TF_R(17) TF_R(29) TF_R(16) TF_R(24)
  x0 += ks2; x1 += k0 + 2u;
  TF_R(13) TF_R(15) TF_R(26) TF_R(6)
  x0 += k0;  x1 += k1 + 3u;
  TF_R(17) TF_R(29) TF_R(16) TF_R(24)
  x0 += k1;  x1 += ks2 + 4u;
  TF_R(13) TF_R(15) TF_R(26) TF_R(6)
  x0 += ks2; x1 += k0 + 5u;
#undef TF_R
  o0 = x0; o1 = x1;
}

// Exact rank value of score = 2.0f + uniform(bits): bits(score) - bits(2.0f).
__device__ __forceinline__ uint32_t m_from_bits(uint32_t bits) {
  float noise = __uint_as_float((bits >> 9) | 0x3F800000u) - 1.0f;
  float score = 2.0f + noise;
  return __float_as_uint(score) - 0x40000000u;  // 0 .. 0x400000 inclusive
}

__device__ __forceinline__ uint32_t pixel_m(uint32_t k0, uint32_t k1, int p) {
  uint32_t b1, b2;
  tf2x32(k0, k1, 0u, (uint32_t)p, b1, b2);
  return m_from_bits(b1 ^ b2);
}

__device__ __forceinline__ float sigf(float x) { return 1.0f / (1.0f + __expf(-x)); }

__device__ __forceinline__ float ldval(const float* __restrict__ img, int r, int c, bool isPred) {
  if (r < 0 || r > HH - 1 || c < 0 || c > WW - 1) return 0.0f;  // conv zero-pad (post-sigmoid)
  float v = img[(size_t)r * WW + c];
  return isPred ? sigf(v) : v;
}

__device__ __forceinline__ uint32_t pack_pt(uint32_t p) {
  return ((p >> 9) << 16) | (p & 511u);
}

// ---------------- K1 ----------------
// Wave spans a full 512-col row: lane owns cols [8*lane, 8*lane+8); v[0]/v[9]
// halos via in-wave shuffles (edge lanes get the conv zero-pad).
// Rolled row loop; named P/Q/R ring (static indices). One raw row in flight,
// promoted one iteration later (hash block covers the latency).
template <bool PRED>
__device__ __forceinline__ void sobel_body(const float* __restrict__ img, int b,
                                           int slice, int t,
                                           unsigned long long* stage, int* s_cn,
                                           int* s_cv) {
  const int lane = t & 63, w = t >> 6;
  const int rbase = slice * ROWS_PER + 8 * w;  // this wave's first compute row
  uint32_t k0, k1;
  tf2x32(0u, 1u, 0u, (uint32_t)b, k0, k1);
  k0 = __builtin_amdgcn_readfirstlane(k0);  // wave-uniform -> pin to SGPR
  k1 = __builtin_amdgcn_readfirstlane(k1);
  const uint32_t ks2 = k0 ^ k1 ^ 0x1BD11BDAu;

  float P[10], Q[10], R[10];  // processed 3-row window (static indices only)
  float4 na, nb;              // raw row in flight (pre-sigmoid, no halos)
  int cnt = 0;
  const uint32_t pbase = (uint32_t)((rbase << 9) + (lane << 3));

  auto issue = [&](int rn) {  // issue-only raw load; no dependent ops
    if ((unsigned)rn < (unsigned)HH) {  // wave-uniform branch
      const float* rp = img + ((size_t)rn << 9) + (lane << 3);
      na = *(const float4*)rp;
      nb = *(const float4*)(rp + 4);
    }
  };
  auto promote = [&](float (&vv)[10], int rn) {  // raw -> processed
    if ((unsigned)rn < (unsigned)HH) {  // wave-uniform branch
      float4 x = na, y = nb;
      if (PRED) {
        x.x = sigf(x.x); x.y = sigf(x.y); x.z = sigf(x.z); x.w = sigf(x.w);
        y.x = sigf(y.x); y.y = sigf(y.y); y.z = sigf(y.z); y.w = sigf(y.w);
      }
      vv[1] = x.x; vv[2] = x.y; vv[3] = x.z; vv[4] = x.w;
      vv[5] = y.x; vv[6] = y.y; vv[7] = y.z; vv[8] = y.w;
      float l = __shfl_up(y.w, 1);
      float r = __shfl_down(x.x, 1);
      vv[0] = (lane == 0) ? 0.0f : l;   // conv zero-pad at col -1
      vv[9] = (lane == 63) ? 0.0f : r;  // conv zero-pad at col 512
    } else {
#pragma unroll
      for (int i = 0; i < 10; ++i) vv[i] = 0.0f;
    }
  };

  // prologue: P = row rbase-1, Q = row rbase; row rbase+1 left in flight
  issue(rbase - 1); promote(P, rbase - 1);
  issue(rbase);     promote(Q, rbase);
  issue(rbase + 1);

#pragma unroll 1
  for (int r = 0; r < 8; ++r) {  // compute row rbase+r — ROLLED
    promote(R, rbase + r + 1);       // consume in-flight raw (loaded 1 body ago)
    if (r < 7) issue(rbase + r + 2); // next raw; reads of na/nb already done
    __builtin_amdgcn_sched_barrier(0);  // pin load issue above the hash block

    const uint32_t prow = pbase + ((uint32_t)r << 9);
    // ---- threefry: 8 explicitly-interleaved chains, 1-inst rotates ----
    uint32_t X0[8], X1[8];
    const uint32_t pk = prow + k1;
#pragma unroll
    for (int j = 0; j < 8; ++j) { X0[j] = k0; X1[j] = pk + (uint32_t)j; }
#define RND(rr)                                                         \
  _Pragma("unroll") for (int j = 0; j < 8; ++j) {                       \
    X0[j] += X1[j];                                                     \
    X1[j] = rotlT<(rr)>(X1[j]) ^ X0[j];                                 \
  }
#define INJ(ka, kb, i)                                                  \
  _Pragma("unroll") for (int j = 0; j < 8; ++j) {                       \
    X0[j] += (ka);                                                      \
    X1[j] += (kb) + (uint32_t)(i);                                      \
  }
    RND(13) RND(15) RND(26) RND(6)  INJ(k1, ks2, 1)
    RND(17) RND(29) RND(16) RND(24) INJ(ks2, k0, 2)
    RND(13) RND(15) RND(26) RND(6)  INJ(k0, k1, 3)
    RND(17) RND(29) RND(16) RND(24) INJ(k1, ks2, 4)
    RND(13) RND(15) RND(26) RND(6)  INJ(ks2, k0, 5)
#undef RND
#undef INJ
    uint32_t bits[8];
#pragma unroll
    for (int j = 0; j < 8; ++j) bits[j] = X0[j] ^ X1[j];

    // ---- sobel + masks ----
    float da[10], e[10];
#pragma unroll
    for (int k = 0; k < 10; ++k) {
      da[k] = R[k] - P[k];
      e[k] = P[k] + 2.0f * Q[k] + R[k];
    }
    uint32_t candmask = 0;
#pragma unroll
    for (int j = 0; j < 8; ++j) {
      float gx = e[j + 2] - e[j];
      float gy = da[j] + 2.0f * da[j + 1] + da[j + 2];
      bool vld = (gx * gx + gy * gy + 1e-8f) > 0.01f;  // sqrt(x)>0.1 <=> x>0.01
      cnt += vld ? 1 : 0;
      candmask |= ((vld && bits[j] >= BITCUT) ? 1u : 0u) << j;
    }
    if (candmask) {  // rare: ~1.2% of pixels -> ONE atomic, then free stores
      int base = atomicAdd(s_cn, __popc(candmask));
      do {
        int j = __ffs(candmask) - 1;
        candmask &= candmask - 1;
        if (base < SLICE_CAP) {
          uint32_t m = m_from_bits(bits[j]);
          stage[base] = ((unsigned long long)m << 32) | (prow + (uint32_t)j);
        }
        ++base;
      } while (candmask);
    }
#pragma unroll
    for (int k = 0; k < 10; ++k) { P[k] = Q[k]; Q[k] = R[k]; }  // rotate ring
  }
#pragma unroll
  for (int o = 32; o > 0; o >>= 1) cnt += __shfl_down(cnt, o);
  if (lane == 0) atomicAdd(s_cv, cnt);
}

__global__ __launch_bounds__(256, 4) void sobel_cand(
    const float* __restrict__ pred, const float* __restrict__ tgt,
    int2* __restrict__ g_scnt, unsigned long long* __restrict__ g_cand) {
  const int bid = blockIdx.x;
  const int b = bid >> 4, s = bid & 15;
  const int t = threadIdx.x;
  __shared__ unsigned long long stage[SLICE_CAP];
  __shared__ int s_cn, s_cv;
  if (t == 0) { s_cn = 0; s_cv = 0; }
  __syncthreads();
  if (b < 64) sobel_body<true>(pred + (size_t)b * NPIX, b, s, t, stage, &s_cn, &s_cv);
  else        sobel_body<false>(tgt + (size_t)(b - 64) * NPIX, b, s, t, stage, &s_cn, &s_cv);
  __syncthreads();
  const int raw = s_cn;
  const int n = raw < SLICE_CAP ? raw : SLICE_CAP;
  for (int i = t; i < n; i += 256) g_cand[(size_t)bid * SLICE_CAP + i] = stage[i];
  if (t == 0) g_scnt[bid] = make_int2(s_cv, raw);
}

// ---------------- K2 resolve (1 block per image-side) ----------------
// Candidates staged ONCE into LDS (compacted, order-free — all selection
// passes are order-insensitive), then 3 passes run out of LDS.
__global__ __launch_bounds__(256) void resolve_kernel(
    const float* __restrict__ pred, const float* __restrict__ tgt,
    const int2* __restrict__ g_scnt, unsigned long long* __restrict__ g_cand,
    uint32_t* __restrict__ g_pts, int* __restrict__ g_counts) {
  const int img = blockIdx.x;
  const int t = threadIdx.x;

  __shared__ unsigned long long cand_s[16 * SLICE_CAP];  // 40 KB
  __shared__ int segc[16];
  __shared__ int s_scx[16], s_scy[16];
  __shared__ int s_info[4];  // cv, cnt_hi_sum, ovf, ncand_rebuilt
  __shared__ int ch[256];
  __shared__ int fh[1024];
  __shared__ int aux[256];
  __shared__ unsigned long long ties[256];
  __shared__ int s_pos, s_nt, s_T1, s_r1, s_T2, s_r2, s_n;

  if (t < 16) {
    int2 v = g_scnt[img * 16 + t];
    s_scx[t] = v.x; s_scy[t] = v.y;
    segc[t] = v.y < SLICE_CAP ? v.y : SLICE_CAP;
  }
  if (t == 0) { s_pos = 0; s_nt = 0; s_n = 0; }
  __syncthreads();
  if (t == 0) {
    int cv = 0, hi = 0, ovf = 0;
    for (int s = 0; s < 16; ++s) {
      cv += s_scx[s]; hi += s_scy[s];
      if (s_scy[s] > SLICE_CAP) ovf = 1;
    }
    s_info[0] = cv; s_info[1] = hi; s_info[2] = ovf;
  }
  __syncthreads();
  const int cv = s_info[0];
  if (cv == 0) {  // center fallback
    if (t == 0) { g_pts[img * NSEL] = (256u << 16) | 256u; g_counts[img] = 1; }
    return;
  }
  const int need = cv < NSEL ? cv : NSEL;
  bool slow = (s_info[2] != 0) || (s_info[1] < need);

  unsigned long long* C = g_cand + (size_t)img * 16 * SLICE_CAP;
  int ncand = 0;

  if (slow) {
    // ---- exact rebuild (statistically never taken): rescan whole image ----
    const bool isPred = img < 64;
    const float* im = isPred ? pred + (size_t)img * NPIX : tgt + (size_t)(img - 64) * NPIX;
    uint32_t k0, k1;
    tf2x32(0u, 1u, 0u, (uint32_t)img, k0, k1);
    ch[t] = 0;
    __syncthreads();
    for (int p = t; p < NPIX; p += 256) {
      int r = p >> 9, c = p & 511;
      float gx = (ldval(im, r - 1, c + 1, isPred) - ldval(im, r - 1, c - 1, isPred)) +
                 2.0f * (ldval(im, r, c + 1, isPred) - ldval(im, r, c - 1, isPred)) +
                 (ldval(im, r + 1, c + 1, isPred) - ldval(im, r + 1, c - 1, isPred));
      float gy = (ldval(im, r + 1, c - 1, isPred) - ldval(im, r - 1, c - 1, isPred)) +
                 2.0f * (ldval(im, r + 1, c, isPred) - ldval(im, r - 1, c, isPred)) +
                 (ldval(im, r + 1, c + 1, isPred) - ldval(im, r - 1, c + 1, isPred));
      if ((gx * gx + gy * gy + 1e-8f) > 0.01f) {
        uint32_t m = pixel_m(k0, k1, p);
        uint32_t cb = m >> 14; if (cb > 255u) cb = 255u;
        atomicAdd(&ch[cb], 1);
      }
    }
    __syncthreads();
    {
      aux[t] = ch[t];
      __syncthreads();
      for (int o = 1; o < 256; o <<= 1) {
        int v = (t + o < 256) ? aux[t + o] : 0;
        __syncthreads();
        aux[t] += v;
        __syncthreads();
      }
      int nx = (t + 1 < 256) ? aux[t + 1] : 0;
      if (aux[t] >= need && nx < need) s_T1 = t;
      __syncthreads();
    }
    const uint32_t Tc = (uint32_t)s_T1;
    if (t == 0) s_info[3] = 0;
    __syncthreads();
    for (int p = t; p < NPIX; p += 256) {
      int r = p >> 9, c = p & 511;
      float gx = (ldval(im, r - 1, c + 1, isPred) - ldval(im, r - 1, c - 1, isPred)) +
                 2.0f * (ldval(im, r, c + 1, isPred) - ldval(im, r, c - 1, isPred)) +
                 (ldval(im, r + 1, c + 1, isPred) - ldval(im, r + 1, c - 1, isPred));
      float gy = (ldval(im, r + 1, c - 1, isPred) - ldval(im, r - 1, c - 1, isPred)) +
                 2.0f * (ldval(im, r + 1, c, isPred) - ldval(im, r - 1, c, isPred)) +
                 (ldval(im, r + 1, c + 1, isPred) - ldval(im, r - 1, c + 1, isPred));
      if ((gx * gx + gy * gy + 1e-8f) > 0.01f) {
        uint32_t m = pixel_m(k0, k1, p);
        uint32_t cb = m >> 14; if (cb > 255u) cb = 255u;
        if (cb >= Tc) {
          int i = atomicAdd(&s_info[3], 1);
          if (i < 16 * SLICE_CAP) C[i] = ((unsigned long long)m << 32) | (uint32_t)p;
        }
      }
    }
    __syncthreads();
    ncand = s_info[3] < 16 * SLICE_CAP ? s_info[3] : 16 * SLICE_CAP;
  }

  // ---- stage candidates into LDS (order-free compaction) ----
  if (slow) {
    for (int i = t; i < ncand; i += 256) cand_s[i] = C[i];
    if (t == 0) s_n = ncand;
  } else {
    for (int i = t; i < 16 * SLICE_CAP; i += 256) {
      int s = i / SLICE_CAP;
      int o = i - s * SLICE_CAP;
      if (o < segc[s]) {
        unsigned long long e = C[i];
        cand_s[atomicAdd(&s_n, 1)] = e;
      }
    }
  }
  // zero histograms while staging is in flight
  ch[t] = 0;
  for (int i = t; i < 1024; i += 256) fh[i] = 0;
  __syncthreads();
  const int n = s_n;

  // ---- selection over LDS candidates ----
  for (int i = t; i < n; i += 256) {
    uint32_t m = (uint32_t)(cand_s[i] >> 32);
    uint32_t cb = m >> 14; if (cb > 255u) cb = 255u;
    atomicAdd(&ch[cb], 1);
  }
  __syncthreads();
  {
    aux[t] = ch[t];
    __syncthreads();
    for (int o = 1; o < 256; o <<= 1) {
      int v = (t + o < 256) ? aux[t + o] : 0;
      __syncthreads();
      aux[t] += v;
      __syncthreads();
    }
    int nx = (t + 1 < 256) ? aux[t + 1] : 0;
    if (aux[t] >= need && nx < need) { s_T1 = t; s_r1 = need - nx; }
    __syncthreads();
  }
  const uint32_t T1 = (uint32_t)s_T1;
  const int r1 = s_r1;
  const uint32_t baseM = T1 << 14;

  for (int i = t; i < n; i += 256) {
    unsigned long long e = cand_s[i];
    uint32_t m = (uint32_t)(e >> 32), p = (uint32_t)e;
    uint32_t cb = m >> 14; if (cb > 255u) cb = 255u;
    if (cb > T1) {
      int pos = atomicAdd(&s_pos, 1);
      g_pts[img * NSEL + pos] = pack_pt(p);
    } else if (cb == T1) {
      uint32_t f = (m - baseM) >> 4; if (f > 1023u) f = 1023u;
      atomicAdd(&fh[f], 1);
    }
  }
  __syncthreads();
  {
    int base = 4 * t, sv = 0;
    for (int j = 3; j >= 0; --j) { sv += fh[base + j]; fh[base + j] = sv; }
    aux[t] = sv;
    __syncthreads();
    for (int o = 1; o < 256; o <<= 1) {
      int v = (t + o < 256) ? aux[t + o] : 0;
      __syncthreads();
      aux[t] += v;
      __syncthreads();
    }
    int add = (t < 255) ? aux[t + 1] : 0;
    for (int j = 0; j < 4; ++j) fh[base + j] += add;
    __syncthreads();
    for (int j = 0; j < 4; ++j) {
      int idx = base + j;
      int sfx = fh[idx];
      int nx = (idx < 1023) ? fh[idx + 1] : 0;
      if (sfx >= r1 && nx < r1) { s_T2 = idx; s_r2 = r1 - nx; }
    }
    __syncthreads();
  }
  const int T2 = s_T2, r2 = s_r2;
  for (int i = t; i < n; i += 256) {
    unsigned long long e = cand_s[i];
    uint32_t m = (uint32_t)(e >> 32), p = (uint32_t)e;
    uint32_t cb = m >> 14; if (cb > 255u) cb = 255u;
    if (cb == T1) {
      uint32_t f = (m - baseM) >> 4; if (f > 1023u) f = 1023u;
      if ((int)f > T2) {
        int pos = atomicAdd(&s_pos, 1);
        g_pts[img * NSEL + pos] = pack_pt(p);
      } else if ((int)f == T2) {
        int j = atomicAdd(&s_nt, 1);
        if (j < 256) ties[j] = e;
      }
    }
  }
  __syncthreads();
  int nt = s_nt < 256 ? s_nt : 256;
  for (int i = t; i < nt; i += 256) {
    unsigned long long e = ties[i];
    uint32_t mi = (uint32_t)(e >> 32), pi = (uint32_t)e;
    int rank = 0;
    for (int j = 0; j < nt; ++j) {
      unsigned long long e2 = ties[j];
      uint32_t mj = (uint32_t)(e2 >> 32), pj = (uint32_t)e2;
      rank += (mj > mi) || (mj == mi && pj < pi);
    }
    if (rank < r2) {
      int pos = atomicAdd(&s_pos, 1);
      g_pts[img * NSEL + pos] = pack_pt(pi);
    }
  }
  __syncthreads();
  if (t == 0) g_counts[img] = s_pos;  // == need
}

// ---------------- K3 ----------------
__global__ __launch_bounds__(256) void haus_kernel(
    const uint32_t* __restrict__ g_pts, const int* __restrict__ g_counts,
    float* __restrict__ g_hpart) {
  const int bid = blockIdx.x;
  const int img = bid >> 3;
  const int dir = (bid >> 2) & 1;
  const int seg = bid & 3;
  const int t = threadIdx.x;
  const int iOwn = dir ? 64 + img : img;
  const int iOth = dir ? img : 64 + img;
  const int nOwn = g_counts[iOwn];
  const int nOth = g_counts[iOth];
  __shared__ float2 o[NSEL];
  __shared__ float red[256];
  for (int i = t; i < nOth; i += 256) {
    uint32_t v = g_pts[iOth * NSEL + i];
    o[i] = make_float2((float)(v >> 16), (float)(v & 0xFFFFu));
  }
  __syncthreads();
  float best = 0.0f;
  const int lo = seg * 250;
  const int hi = min(nOwn, lo + 250);
  for (int i = lo + t; i < hi; i += 256) {
    uint32_t v = g_pts[iOwn * NSEL + i];
    float pr = (float)(v >> 16), pc = (float)(v & 0xFFFFu);
    // 4 independent accumulators: break the serial fmin dependency chain
    float mn0 = 3.4e38f, mn1 = 3.4e38f, mn2 = 3.4e38f, mn3 = 3.4e38f;
    int j = 0;
    for (; j + 3 < nOth; j += 4) {
      float dr0 = pr - o[j].x,     dc0 = pc - o[j].y;
      float dr1 = pr - o[j + 1].x, dc1 = pc - o[j + 1].y;
      float dr2 = pr - o[j + 2].x, dc2 = pc - o[j + 2].y;
      float dr3 = pr - o[j + 3].x, dc3 = pc - o[j + 3].y;
      mn0 = fminf(mn0, dr0 * dr0 + dc0 * dc0);
      mn1 = fminf(mn1, dr1 * dr1 + dc1 * dc1);
      mn2 = fminf(mn2, dr2 * dr2 + dc2 * dc2);
      mn3 = fminf(mn3, dr3 * dr3 + dc3 * dc3);
    }
    for (; j < nOth; ++j) {
      float dr = pr - o[j].x, dc = pc - o[j].y;
      mn0 = fminf(mn0, dr * dr + dc * dc);
    }
    float mn = fminf(fminf(mn0, mn1), fminf(mn2, mn3));
    best = fmaxf(best, mn);
  }
  red[t] = best;
  __syncthreads();
  for (int st = 128; st > 0; st >>= 1) {
    if (t < st) red[t] = fmaxf(red[t], red[t + st]);
    __syncthreads();
  }
  if (t == 0) g_hpart[bid] = red[0];
}

// ---------------- K4 ----------------
__global__ __launch_bounds__(64) void fin_kernel(const float* __restrict__ g_hpart,
                                                 float* __restrict__ out) {
  const int t = threadIdx.x;  // one thread per image
  float mx = 0.0f;
  for (int j = 0; j < 8; ++j) mx = fmaxf(mx, g_hpart[t * 8 + j]);
  float diag = sqrtf((float)(HH * HH + WW * WW));
  float hd = sqrtf(fmaxf(mx, 0.0f)) / diag;
  hd = fminf(fmaxf(hd, 0.0f), 0.1f);
  float s = hd;
  for (int o = 32; o > 0; o >>= 1) s += __shfl_down(s, o);
  if (t == 0) out[0] = s * 0.015625f;
}

// ---------------- workspace layout (bytes) — nothing pre-zeroed ----------
#define WS_SCNT   0u                          // 2048*8 = 16384
#define WS_COUNTS 16384u                      // 512
#define WS_HPART  (WS_COUNTS + 512u)          // 2048
#define WS_PTS    (WS_HPART + 2048u)          // 512000
#define WS_CAND   (WS_PTS + 512000u)          // 2048*320*8 = 5242880  (~5.5 MB total)

extern "C" void kernel_launch(void* const* d_in, const int* in_sizes, int n_in,
                              void* d_out, int out_size, void* d_ws, size_t ws_size,
                              hipStream_t stream) {
  const float* pred = (const float*)d_in[0];
  const float* tgt = (const float*)d_in[1];
  float* out = (float*)d_out;
  char* ws = (char*)d_ws;
  int2* g_scnt = (int2*)(ws + WS_SCNT);
  int* g_counts = (int*)(ws + WS_COUNTS);
  float* g_hpart = (float*)(ws + WS_HPART);
  uint32_t* g_pts = (uint32_t*)(ws + WS_PTS);
  unsigned long long* g_cand = (unsigned long long*)(ws + WS_CAND);

  sobel_cand<<<2048, 256, 0, stream>>>(pred, tgt, g_scnt, g_cand);
  resolve_kernel<<<128, 256, 0, stream>>>(pred, tgt, g_scnt, g_cand, g_pts, g_counts);
  haus_kernel<<<512, 256, 0, stream>>>(g_pts, g_counts, g_hpart);
  fin_kernel<<<1, 64, 0, stream>>>(g_hpart, out);
}